// Round 9
// baseline (169.967 us; speedup 1.0000x reference)
//
#include <hip/hip_runtime.h>
#include <math.h>

// FeedForwardQuantum, analytically collapsed circuit:
//   z_j = cos(theta_j) * cos(x.W1_j + b1_j)
//   ex[w] = prod_{j<=w} z_j (w>=1); ex[0] = prod_{j=1..7} z_j
//   out = relu(ex @ W2^T + b2)
//
// Single kernel, 2-stage hand-unrolled software pipeline per wave (2 tokens
// per stage, 4 tokens/wave). Stage B's x loads are issued after GEMM1(A)
// (pinned by sched_barrier) so they overlap A's reduce/GEMM2/stores, and A's
// NT stores drain under B's compute -> mixed HBM stream instead of
// read-burst / idle / write-burst lockstep.

constexpr int EMBED = 768;
constexpr int NQ    = 8;
constexpr int BLOCK = 256;           // 4 waves
constexpr int WAVES = 4;
constexpr int TPW   = 4;             // tokens per wave (2 stages x 2)
constexpr int TPB   = WAVES * TPW;   // 16 tokens per block

typedef float vfloat4 __attribute__((ext_vector_type(4)));

// NOTE: macro params must not be named x/y/z/w (member-accessor collision)
#define DOT4(va, vb, sv) sv = fmaf((va).x, (vb).x, fmaf((va).y, (vb).y, \
                         fmaf((va).z, (vb).z, fmaf((va).w, (vb).w, (sv)))))

// packed butterfly: 10 shuffles -> every lane holds full sum for q = lane&7
#define PACKED_REDUCE(acc, S) {                                          \
    float k0 = c0 ? acc[1] : acc[0], g0 = c0 ? acc[0] : acc[1];          \
    float k1 = c0 ? acc[3] : acc[2], g1 = c0 ? acc[2] : acc[3];          \
    float k2 = c0 ? acc[5] : acc[4], g2 = c0 ? acc[4] : acc[5];          \
    float k3 = c0 ? acc[7] : acc[6], g3 = c0 ? acc[6] : acc[7];          \
    float v0 = k0 + __shfl_xor(g0, 1, 64);                               \
    float v1 = k1 + __shfl_xor(g1, 1, 64);                               \
    float v2 = k2 + __shfl_xor(g2, 1, 64);                               \
    float v3 = k3 + __shfl_xor(g3, 1, 64);                               \
    float ka = c1 ? v1 : v0, ga = c1 ? v0 : v1;                          \
    float kb = c1 ? v3 : v2, gb = c1 ? v2 : v3;                          \
    float u0 = ka + __shfl_xor(ga, 2, 64);                               \
    float u1 = kb + __shfl_xor(gb, 2, 64);                               \
    float kc = c2 ? u1 : u0, gc = c2 ? u0 : u1;                          \
    float s  = kc + __shfl_xor(gc, 4, 64);                               \
    s += __shfl_xor(s, 8, 64);                                           \
    s += __shfl_xor(s, 16, 64);                                          \
    s += __shfl_xor(s, 32, 64);                                          \
    S = s; }

// z publish + sorted readback + prefix products + GEMM2 + relu + NT stores
// for one stage holding sums S0 (token t0v) and S1 (token t1v).
#define STAGE_TAIL(S0, S1, t0v, t1v) {                                   \
    const float Ssel = osel ? (S1) : (S0);                               \
    const float zval = costh * __cosf(Ssel + b1q);                       \
    zbuf[wave][osel][q_own] = zval;                                      \
    float ex0[NQ], ex1[NQ];                                              \
    {                                                                    \
        const float4 za = ((const float4*)zbuf[wave][0])[0];             \
        const float4 zb = ((const float4*)zbuf[wave][0])[1];             \
        const float zq[NQ] = { za.x, za.y, za.z, za.w,                   \
                               zb.x, zb.y, zb.z, zb.w };                 \
        float p = zq[0];                                                 \
        _Pragma("unroll")                                                \
        for (int q = 1; q < NQ; ++q) { p *= zq[q]; ex0[q] = p; }         \
        float sfx = zq[1];                                               \
        _Pragma("unroll")                                                \
        for (int q = 2; q < NQ; ++q) sfx *= zq[q];                       \
        ex0[0] = sfx;                                                    \
    }                                                                    \
    {                                                                    \
        const float4 za = ((const float4*)zbuf[wave][1])[0];             \
        const float4 zb = ((const float4*)zbuf[wave][1])[1];             \
        const float zq[NQ] = { za.x, za.y, za.z, za.w,                   \
                               zb.x, zb.y, zb.z, zb.w };                 \
        float p = zq[0];                                                 \
        _Pragma("unroll")                                                \
        for (int q = 1; q < NQ; ++q) { p *= zq[q]; ex1[q] = p; }         \
        float sfx = zq[1];                                               \
        _Pragma("unroll")                                                \
        for (int q = 2; q < NQ; ++q) sfx *= zq[q];                       \
        ex1[0] = sfx;                                                    \
    }                                                                    \
    _Pragma("unroll")                                                    \
    for (int k = 0; k < 3; ++k) {                                        \
        const int idx = lane + 64 * k;                                   \
        float4 r0 = bb[k], r1 = bb[k];                                   \
        _Pragma("unroll")                                                \
        for (int q = 0; q < NQ; ++q) {                                   \
            const float4 wv = ((const float4*)&w2t[q][0])[idx];          \
            r0.x = fmaf(ex0[q], wv.x, r0.x);                             \
            r0.y = fmaf(ex0[q], wv.y, r0.y);                             \
            r0.z = fmaf(ex0[q], wv.z, r0.z);                             \
            r0.w = fmaf(ex0[q], wv.w, r0.w);                             \
            r1.x = fmaf(ex1[q], wv.x, r1.x);                             \
            r1.y = fmaf(ex1[q], wv.y, r1.y);                             \
            r1.z = fmaf(ex1[q], wv.z, r1.z);                             \
            r1.w = fmaf(ex1[q], wv.w, r1.w);                             \
        }                                                                \
        vfloat4 o0 = { fmaxf(r0.x, 0.f), fmaxf(r0.y, 0.f),               \
                       fmaxf(r0.z, 0.f), fmaxf(r0.w, 0.f) };             \
        vfloat4 o1 = { fmaxf(r1.x, 0.f), fmaxf(r1.y, 0.f),               \
                       fmaxf(r1.z, 0.f), fmaxf(r1.w, 0.f) };             \
        __builtin_nontemporal_store(o0, (vfloat4*)(out + (size_t)(t0v) * EMBED) + idx); \
        __builtin_nontemporal_store(o1, (vfloat4*)(out + (size_t)(t1v) * EMBED) + idx); \
    } }

__global__ __launch_bounds__(BLOCK, 4) void ffq_kernel(
    const float* __restrict__ x,  const float* __restrict__ W1,
    const float* __restrict__ b1, const float* __restrict__ theta,
    const float* __restrict__ W2, const float* __restrict__ b2,
    float* __restrict__ out, int ntok)
{
    __shared__ float w2t[NQ][EMBED];                       // transposed W2 (24 KB)
    __shared__ __align__(16) float zbuf[WAVES][2][NQ];     // per-wave z broadcast

    const int tid  = threadIdx.x;
    const int wave = tid >> 6;
    const int lane = tid & 63;
    const int tbase = (blockIdx.x * WAVES + wave) * TPW;

    const int tA0 = min(tbase + 0, ntok - 1);
    const int tA1 = min(tbase + 1, ntok - 1);
    const int tB0 = min(tbase + 2, ntok - 1);
    const int tB1 = min(tbase + 3, ntok - 1);

    // ---- stage-A x loads (named regs) ----
    const float4* x4 = (const float4*)x;
    const float4 xa0 = x4[(size_t)tA0 * (EMBED / 4) + lane];
    const float4 xa1 = x4[(size_t)tA0 * (EMBED / 4) + lane + 64];
    const float4 xa2 = x4[(size_t)tA0 * (EMBED / 4) + lane + 128];
    const float4 xb0 = x4[(size_t)tA1 * (EMBED / 4) + lane];
    const float4 xb1 = x4[(size_t)tA1 * (EMBED / 4) + lane + 64];
    const float4 xb2 = x4[(size_t)tA1 * (EMBED / 4) + lane + 128];

    // ---- stage W2 transposed (once): coalesced reads, scalar scatter writes ----
    {
        const float4* W24 = (const float4*)W2;
        for (int i = tid; i < EMBED * NQ / 4; i += BLOCK) {
            const float4 v = W24[i];
            const int f = 4 * i;                 // flat = e*8 + q
            w2t[(f + 0) & 7][(f + 0) >> 3] = v.x;
            w2t[(f + 1) & 7][(f + 1) >> 3] = v.y;
            w2t[(f + 2) & 7][(f + 2) >> 3] = v.z;
            w2t[(f + 3) & 7][(f + 3) >> 3] = v.w;
        }
    }

    const int q_own = lane & 7;
    const float costh = __cosf(theta[q_own]);
    const float b1q   = b1[q_own];
    const int osel = (lane >> 3) & 1;
    const bool c0 = lane & 1, c1 = lane & 2, c2 = lane & 4;

    // hoist b2
    const float4* b24 = (const float4*)b2;
    float4 bb[3];
    #pragma unroll
    for (int k = 0; k < 3; ++k) bb[k] = b24[lane + 64 * k];

    __syncthreads();   // w2t ready (only block-wide barrier)

    // ---- GEMM1(A): W1 shared across the stage's 2 tokens ----
    const float4* W14 = (const float4*)W1;
    float accA0[NQ], accA1[NQ];
    #pragma unroll
    for (int q = 0; q < NQ; ++q) {
        const float4 w0 = W14[q * (EMBED / 4) + lane];
        const float4 w1 = W14[q * (EMBED / 4) + lane + 64];
        const float4 w2 = W14[q * (EMBED / 4) + lane + 128];
        float s0 = 0.f, s1 = 0.f;
        DOT4(xa0, w0, s0); DOT4(xa1, w1, s0); DOT4(xa2, w2, s0);
        DOT4(xb0, w0, s1); DOT4(xb1, w1, s1); DOT4(xb2, w2, s1);
        accA0[q] = s0; accA1[q] = s1;
    }

    // ---- pin: stage-B loads may not be hoisted above this point ----
    __builtin_amdgcn_sched_barrier(0);

    // ---- stage-B x loads: in flight during A's reduce/GEMM2/stores ----
    const float4 ya0 = x4[(size_t)tB0 * (EMBED / 4) + lane];
    const float4 ya1 = x4[(size_t)tB0 * (EMBED / 4) + lane + 64];
    const float4 ya2 = x4[(size_t)tB0 * (EMBED / 4) + lane + 128];
    const float4 yb0 = x4[(size_t)tB1 * (EMBED / 4) + lane];
    const float4 yb1 = x4[(size_t)tB1 * (EMBED / 4) + lane + 64];
    const float4 yb2 = x4[(size_t)tB1 * (EMBED / 4) + lane + 128];

    // ---- finish stage A ----
    float SA0, SA1;
    PACKED_REDUCE(accA0, SA0);
    PACKED_REDUCE(accA1, SA1);
    STAGE_TAIL(SA0, SA1, tA0, tA1);

    // ---- stage B: GEMM1 (W1 now L1-hot), reduce, tail ----
    float accB0[NQ], accB1[NQ];
    #pragma unroll
    for (int q = 0; q < NQ; ++q) {
        const float4 w0 = W14[q * (EMBED / 4) + lane];
        const float4 w1 = W14[q * (EMBED / 4) + lane + 64];
        const float4 w2 = W14[q * (EMBED / 4) + lane + 128];
        float s0 = 0.f, s1 = 0.f;
        DOT4(ya0, w0, s0); DOT4(ya1, w1, s0); DOT4(ya2, w2, s0);
        DOT4(yb0, w0, s1); DOT4(yb1, w1, s1); DOT4(yb2, w2, s1);
        accB0[q] = s0; accB1[q] = s1;
    }

    float SB0, SB1;
    PACKED_REDUCE(accB0, SB0);
    PACKED_REDUCE(accB1, SB1);
    STAGE_TAIL(SB0, SB1, tB0, tB1);
}

extern "C" void kernel_launch(void* const* d_in, const int* in_sizes, int n_in,
                              void* d_out, int out_size, void* d_ws, size_t ws_size,
                              hipStream_t stream) {
    const float* x     = (const float*)d_in[0];
    const float* W1    = (const float*)d_in[1];
    const float* b1    = (const float*)d_in[2];
    const float* theta = (const float*)d_in[3];
    const float* W2    = (const float*)d_in[4];
    const float* b2    = (const float*)d_in[5];
    float* out = (float*)d_out;

    const int ntok = in_sizes[0] / EMBED;          // 16384
    const int grid = (ntok + TPB - 1) / TPB;       // 1024 = 4 blocks/CU
    hipLaunchKernelGGL(ffq_kernel, dim3(grid), dim3(BLOCK), 0, stream,
                       x, W1, b1, theta, W2, b2, out, ntok);
}

// Round 10
// 24.571 us; speedup vs baseline: 6.9174x; 6.9174x over previous
//
#include <hip/hip_runtime.h>
#include <math.h>

// FeedForwardQuantum, analytically collapsed circuit:
//   z_j = cos(theta_j) * cos(x.W1_j + b1_j)
//   ex[w] = prod_{j<=w} z_j (w>=1); ex[0] = prod_{j=1..7} z_j
//   out = relu(ex @ W2^T + b2)
//
// R4 structure (best: 24.4us) with ONE change: stores are plain float4
// (allocate in L2/L3) instead of nontemporal (stream to HBM). x+out = 100MB
// fits the 256MB Infinity Cache, so steady-state replays should run the
// write phase at cache speed instead of HBM speed.

constexpr int EMBED = 768;
constexpr int NQ    = 8;
constexpr int BLOCK = 256;            // 4 waves
constexpr int WAVES = 4;
constexpr int TPT   = 4;              // tokens per wave, processed concurrently
constexpr int TPB   = WAVES * TPT;    // 16 tokens/block

__global__ __launch_bounds__(BLOCK, 4) void ffq_kernel(
    const float* __restrict__ x,  const float* __restrict__ W1,
    const float* __restrict__ b1, const float* __restrict__ theta,
    const float* __restrict__ W2, const float* __restrict__ b2,
    float* __restrict__ out, int ntok)
{
    __shared__ float w2t[NQ][EMBED];          // transposed W2 (24 KB)
    __shared__ float zbuf[WAVES][TPT][NQ];    // per-wave z broadcast (512 B)

    const int tid = threadIdx.x;

    // ---- stage W2 transposed: coalesced float4 reads, scalar scatter writes ----
    {
        const float4* W24 = (const float4*)W2;
        for (int i = tid; i < EMBED * NQ / 4; i += BLOCK) {
            const float4 v = W24[i];
            const int f = 4 * i;                 // flat = e*8 + q
            w2t[(f + 0) & 7][(f + 0) >> 3] = v.x;
            w2t[(f + 1) & 7][(f + 1) >> 3] = v.y;
            w2t[(f + 2) & 7][(f + 2) >> 3] = v.z;
            w2t[(f + 3) & 7][(f + 3) >> 3] = v.w;
        }
    }

    const int wave  = tid >> 6;
    const int lane  = tid & 63;
    const int q_own = lane & 7;
    const float costh = __cosf(theta[q_own]);
    const float b1q   = b1[q_own];

    const int t0 = (blockIdx.x * WAVES + wave) * TPT;
    int tk[TPT];
    #pragma unroll
    for (int it = 0; it < TPT; ++it) {
        int t = t0 + it; tk[it] = (t < ntok) ? t : (ntok - 1);   // clamp: benign dup
    }

    // ---- issue all x loads up front (12 KB in flight per wave) ----
    const float4* x4 = (const float4*)x;
    float4 xv[TPT][3];
    #pragma unroll
    for (int it = 0; it < TPT; ++it)
        #pragma unroll
        for (int k = 0; k < 3; ++k)
            xv[it][k] = x4[(size_t)tk[it] * (EMBED / 4) + lane + 64 * k];

    __syncthreads();   // w2t ready

    // ---- GEMM1 partials: W1 from global (L1-resident), shared across tokens ----
    const float4* W14 = (const float4*)W1;
    float acc[TPT][NQ];
    #pragma unroll
    for (int it = 0; it < TPT; ++it)
        #pragma unroll
        for (int q = 0; q < NQ; ++q) acc[it][q] = 0.f;

    #pragma unroll
    for (int k = 0; k < 3; ++k) {
        const int idx = lane + 64 * k;
        #pragma unroll
        for (int q = 0; q < NQ; ++q) {
            const float4 w = W14[q * (EMBED / 4) + idx];
            #pragma unroll
            for (int it = 0; it < TPT; ++it) {
                acc[it][q] = fmaf(xv[it][k].x, w.x, fmaf(xv[it][k].y, w.y,
                             fmaf(xv[it][k].z, w.z, fmaf(xv[it][k].w, w.w, acc[it][q]))));
            }
        }
    }

    // ---- packed reduce: 10 shuffles/token -> lane holds full sum for q = lane&7 ----
    const bool c0 = lane & 1, c1 = lane & 2, c2 = lane & 4;
    float S[TPT];
    #pragma unroll
    for (int it = 0; it < TPT; ++it) {
        float k0 = c0 ? acc[it][1] : acc[it][0], g0 = c0 ? acc[it][0] : acc[it][1];
        float k1 = c0 ? acc[it][3] : acc[it][2], g1 = c0 ? acc[it][2] : acc[it][3];
        float k2 = c0 ? acc[it][5] : acc[it][4], g2 = c0 ? acc[it][4] : acc[it][5];
        float k3 = c0 ? acc[it][7] : acc[it][6], g3 = c0 ? acc[it][6] : acc[it][7];
        float v0 = k0 + __shfl_xor(g0, 1, 64);
        float v1 = k1 + __shfl_xor(g1, 1, 64);
        float v2 = k2 + __shfl_xor(g2, 1, 64);
        float v3 = k3 + __shfl_xor(g3, 1, 64);
        float ka = c1 ? v1 : v0, ga = c1 ? v0 : v1;
        float kb = c1 ? v3 : v2, gb = c1 ? v2 : v3;
        float u0 = ka + __shfl_xor(ga, 2, 64);
        float u1 = kb + __shfl_xor(gb, 2, 64);
        float kc = c2 ? u1 : u0, gc = c2 ? u0 : u1;
        float s  = kc + __shfl_xor(gc, 4, 64);
        s += __shfl_xor(s, 8, 64);
        s += __shfl_xor(s, 16, 64);
        s += __shfl_xor(s, 32, 64);
        S[it] = s;   // full sum of q_in[token it][q_own]
    }

    // ---- one cosf per lane; octet o publishes token (o&3)'s z[q] to LDS ----
    const int osel = (lane >> 3) & (TPT - 1);
    const bool s0 = osel & 1, s1 = osel & 2;
    const float Ssel = s1 ? (s0 ? S[3] : S[2]) : (s0 ? S[1] : S[0]);
    const float zval = costh * __cosf(Ssel + b1q);
    zbuf[wave][osel][q_own] = zval;    // octets o and o+4 write identical values

    // ---- read back sorted z[8] per token (broadcast b128), prefix products ----
    float ex[TPT][NQ];
    #pragma unroll
    for (int it = 0; it < TPT; ++it) {
        const float4 za = ((const float4*)zbuf[wave][it])[0];
        const float4 zb = ((const float4*)zbuf[wave][it])[1];
        const float zq[NQ] = { za.x, za.y, za.z, za.w, zb.x, zb.y, zb.z, zb.w };
        float p = zq[0];
        #pragma unroll
        for (int q = 1; q < NQ; ++q) { p *= zq[q]; ex[it][q] = p; }
        float sfx = zq[1];
        #pragma unroll
        for (int q = 2; q < NQ; ++q) sfx *= zq[q];
        ex[it][0] = sfx;
    }

    // ---- GEMM2 + bias + relu: conflict-free b128 LDS reads, cached stores ----
    const float4* b24 = (const float4*)b2;
    #pragma unroll
    for (int k = 0; k < 3; ++k) {
        const int idx = lane + 64 * k;
        const float4 bb = b24[idx];
        float4 r[TPT];
        #pragma unroll
        for (int it = 0; it < TPT; ++it) r[it] = bb;
        #pragma unroll
        for (int q = 0; q < NQ; ++q) {
            const float4 w = ((const float4*)&w2t[q][0])[idx];
            #pragma unroll
            for (int it = 0; it < TPT; ++it) {
                r[it].x = fmaf(ex[it][q], w.x, r[it].x);
                r[it].y = fmaf(ex[it][q], w.y, r[it].y);
                r[it].z = fmaf(ex[it][q], w.z, r[it].z);
                r[it].w = fmaf(ex[it][q], w.w, r[it].w);
            }
        }
        #pragma unroll
        for (int it = 0; it < TPT; ++it) {
            float4 o = make_float4(fmaxf(r[it].x, 0.f), fmaxf(r[it].y, 0.f),
                                   fmaxf(r[it].z, 0.f), fmaxf(r[it].w, 0.f));
            ((float4*)(out + (size_t)tk[it] * EMBED))[idx] = o;
        }
    }
}

extern "C" void kernel_launch(void* const* d_in, const int* in_sizes, int n_in,
                              void* d_out, int out_size, void* d_ws, size_t ws_size,
                              hipStream_t stream) {
    const float* x     = (const float*)d_in[0];
    const float* W1    = (const float*)d_in[1];
    const float* b1    = (const float*)d_in[2];
    const float* theta = (const float*)d_in[3];
    const float* W2    = (const float*)d_in[4];
    const float* b2    = (const float*)d_in[5];
    float* out = (float*)d_out;

    const int ntok = in_sizes[0] / EMBED;          // 16384
    const int grid = (ntok + TPB - 1) / TPB;       // 1024 = 4 blocks/CU
    hipLaunchKernelGGL(ffq_kernel, dim3(grid), dim3(BLOCK), 0, stream,
                       x, W1, b1, theta, W2, b2, out, ntok);
}